// Round 7
// baseline (228.857 us; speedup 1.0000x reference)
//
#include <hip/hip_runtime.h>
#include <math.h>

#define B_  512
#define I_  8
#define C_  1152
#define J_  10
#define S_  16
#define K1  9216
#define NKB 288     // sgemm K-blocks (K=9216/32)
#define KBT 16      // tgemm K-blocks (K=512/32)
#define NBL 360     // main kernel grid (co-resident: <= 2 blocks/CU x 256)
#define NT  512

typedef short short8 __attribute__((ext_vector_type(8)));
typedef float floatx4 __attribute__((ext_vector_type(4)));

__device__ inline unsigned short f2bf(float f) {
    unsigned int u = __float_as_uint(f);
    return (unsigned short)((u + 0x7FFFu + ((u >> 16) & 1u)) >> 16);
}
__device__ inline unsigned int pack2(float a, float b) {
    return (unsigned int)f2bf(a) | ((unsigned int)f2bf(b) << 16);
}

// Grid barrier with NO cache maintenance: workgroup fences (waitcnt only),
// relaxed agent RMW/loads (serviced at LLC). Cross-phase data goes through
// LLC explicitly (agent atomics), so no inv/wb is needed here.
__device__ __forceinline__ void grid_bar(int* bar) {
    __builtin_amdgcn_fence(__ATOMIC_RELEASE, "workgroup");   // drain this wave's stores
    __syncthreads();
    if (threadIdx.x == 0) {
        int g = __hip_atomic_load(&bar[1], __ATOMIC_RELAXED, __HIP_MEMORY_SCOPE_AGENT);
        int old = __hip_atomic_fetch_add(&bar[0], 1, __ATOMIC_RELAXED, __HIP_MEMORY_SCOPE_AGENT);
        if (old == NBL - 1) {
            __hip_atomic_store(&bar[0], 0, __ATOMIC_RELAXED, __HIP_MEMORY_SCOPE_AGENT);
            __hip_atomic_store(&bar[1], g + 1, __ATOMIC_RELAXED, __HIP_MEMORY_SCOPE_AGENT);
        } else {
            int spins = 0;
            while (__hip_atomic_load(&bar[1], __ATOMIC_RELAXED, __HIP_MEMORY_SCOPE_AGENT) == g) {
                __builtin_amdgcn_s_sleep(1);
                if (++spins > (1 << 20)) break;   // failsafe: fail visibly, don't hang
            }
        }
    }
    __syncthreads();
    __builtin_amdgcn_fence(__ATOMIC_ACQUIRE, "workgroup");
}

// ---------------------------------------------------------------------------
// PACK (unchanged from r6, plus barrier-word zeroing in the last task)
__global__ __launch_bounds__(512) void k_pack(const float* __restrict__ x,
                                              const float* __restrict__ W,
                                              uint4* __restrict__ Bs,
                                              uint4* __restrict__ Bt,
                                              uint4* __restrict__ Wf,
                                              unsigned short* __restrict__ W2,
                                              float* __restrict__ b_ij,
                                              int* __restrict__ bar) {
    __shared__ float lds[10240];
    const int task = blockIdx.x;
    const int t = threadIdx.x;
    const int w = t >> 6, L = t & 63, quad = L >> 4;

    if (task < 576) {                       // ---- x tile -> Bs + Bt
        const int bt = task / 36, kt = task % 36;
        const int b0 = bt * 32, k0 = kt * 256;
        #pragma unroll
        for (int p = 0; p < 4; p++) {
            int f4 = p * 512 + t;
            int row = f4 >> 6, c4 = (f4 & 63) << 2;
            *(float4*)&lds[row * 260 + c4] =
                *(const float4*)&x[(size_t)(b0 + row) * K1 + k0 + c4];
        }
        __syncthreads();
        #pragma unroll
        for (int p = 0; p < 2; p++) {
            const int bl = p * 16 + (L & 15);
            const float* s = &lds[bl * 260 + w * 32 + quad * 8];
            uint4 o;
            o.x = pack2(s[0], s[1]); o.y = pack2(s[2], s[3]);
            o.z = pack2(s[4], s[5]); o.w = pack2(s[6], s[7]);
            Bs[((size_t)(bt * 2 + p) * NKB + kt * 8 + w) * 64 + L] = o;
        }
        #pragma unroll
        for (int p = 0; p < 2; p++) {
            const int ntl = w * 2 + p;
            const int nl = ntl * 16 + (L & 15);
            float v[8];
            #pragma unroll
            for (int e = 0; e < 8; e++) v[e] = lds[(quad * 8 + e) * 260 + nl];
            uint4 o;
            o.x = pack2(v[0], v[1]); o.y = pack2(v[2], v[3]);
            o.z = pack2(v[4], v[5]); o.w = pack2(v[6], v[7]);
            Bt[((size_t)(kt * 16 + ntl) * KBT + bt) * 64 + L] = o;
        }
    } else if (task < 720) {                // ---- W chunk -> Wf + W2
        const int c0 = (task - 576) * 8;
        #pragma unroll
        for (int p = 0; p < 5; p++) {
            int f4 = p * 512 + t;
            int cc = f4 / 320, off4 = (f4 % 320) << 2;
            *(float4*)&lds[cc * 1280 + off4] =
                *(const float4*)&W[(size_t)(c0 + cc) * 1280 + off4];
        }
        __syncthreads();
        #pragma unroll
        for (int p = 0; p < 3; p++) {
            int o = p * 512 + t;
            if (o < 1280) {
                int j = o >> 7, i = (o >> 4) & 7, m = o & 15;
                int k0w = i * C_ + c0;
                int Lw = m | (((k0w >> 3) & 3) << 4);
                float v[8];
                #pragma unroll
                for (int e = 0; e < 8; e++)
                    v[e] = lds[e * 1280 + j * 128 + m * 8 + i];
                uint4 og;
                og.x = pack2(v[0], v[1]); og.y = pack2(v[2], v[3]);
                og.z = pack2(v[4], v[5]); og.w = pack2(v[6], v[7]);
                Wf[((size_t)j * NKB + (k0w >> 5)) * 64 + Lw] = og;
            }
        }
        #pragma unroll
        for (int p = 0; p < 2; p++) {
            int o = p * 512 + t;
            if (o < 640) {
                int j = o >> 6, i = (o >> 3) & 7, cc = o & 7;
                unsigned int r8[8];
                #pragma unroll
                for (int h = 0; h < 8; h++)
                    r8[h] = pack2(lds[cc * 1280 + j * 128 + (2 * h) * 8 + i],
                                  lds[cc * 1280 + j * 128 + (2 * h + 1) * 8 + i]);
                unsigned short* dst = W2 + ((size_t)(j * 8 + i) * C_ + c0 + cc) * 16;
                *(uint4*)dst       = make_uint4(r8[0], r8[1], r8[2], r8[3]);
                *(uint4*)(dst + 8) = make_uint4(r8[4], r8[5], r8[6], r8[7]);
            }
        }
    } else {                                // ---- zero b_ij + barrier words
        for (int idx = t; idx < C_ * J_; idx += 512) b_ij[idx] = 0.0f;
        if (t < 16) bar[t] = 0;
    }
}

// ---------------------------------------------------------------------------
// MAIN: s0 | t0 | s1 | t1 | s2 with 4 LLC-mediated grid barriers.
// Cross-barrier data (Vf, b_ij) via relaxed agent atomics (LLC, always fresh);
// read-only packed data (Bs/Bt/Wf/W2) via normal cached loads (never stale).
__global__ __launch_bounds__(NT, 4) void k_main(
    const short8* __restrict__ Wf, const short8* __restrict__ Bs,
    const short8* __restrict__ Bt, const unsigned short* __restrict__ W2,
    unsigned int* __restrict__ Vf_dw, float* __restrict__ b_ij,
    float* __restrict__ out, int* __restrict__ bar)
{
    __shared__ float smf[6400];   // 25.6 KB
    unsigned int* smu = (unsigned int*)smf;
    const int bid = blockIdx.x, t = threadIdx.x;
    const int w = t >> 6, L = t & 63, quad = L >> 4;

    for (int it = 0; it < 3; it++) {
        // ================= S phase: 320 tasks (j, nt) =================
        for (int task = bid; task < 320; task += NBL) {
            __syncthreads();
            const int j = task >> 5, nt = task & 31;
            if (it > 0) {
                for (int c = t; c < C_; c += NT) {
                    float bv[J_], mx = -1e30f;
                    #pragma unroll
                    for (int jj = 0; jj < J_; jj++) {
                        bv[jj] = __hip_atomic_load(&b_ij[c * J_ + jj],
                                 __ATOMIC_RELAXED, __HIP_MEMORY_SCOPE_AGENT);
                        mx = fmaxf(mx, bv[jj]);
                    }
                    float sum = 0.0f;
                    #pragma unroll
                    for (int jj = 0; jj < J_; jj++) sum += __expf(bv[jj] - mx);
                    smf[c] = __expf(bv[j] - mx) / sum;
                }
            }
            __syncthreads();
            const short8* pA = Wf + ((size_t)j * NKB + w * 36) * 64 + L;
            const short8* pB = Bs + ((size_t)nt * NKB + w * 36) * 64 + L;
            floatx4 acc = {0.f, 0.f, 0.f, 0.f};
            if (it > 0) {
                #pragma unroll 4
                for (int i = 0; i < 36; i++) {
                    short8 a = pA[i * 64];
                    const int cb = i * 32 + quad * 8;      // (w*36*32)%1152==0
                    float4 cl = *(const float4*)&smf[cb];
                    float4 ch = *(const float4*)&smf[cb + 4];
                    float cn8[8] = {cl.x, cl.y, cl.z, cl.w, ch.x, ch.y, ch.z, ch.w};
                    unsigned int* au = (unsigned int*)&a;
                    short8 a2; unsigned int* ao = (unsigned int*)&a2;
                    #pragma unroll
                    for (int h = 0; h < 4; h++) {
                        float f0 = __uint_as_float(au[h] << 16)         * cn8[2 * h];
                        float f1 = __uint_as_float(au[h] & 0xffff0000u) * cn8[2 * h + 1];
                        ao[h] = pack2(f0, f1);
                    }
                    acc = __builtin_amdgcn_mfma_f32_16x16x32_bf16(a2, pB[i * 64], acc, 0, 0, 0);
                }
            } else {
                #pragma unroll 4
                for (int i = 0; i < 36; i++)
                    acc = __builtin_amdgcn_mfma_f32_16x16x32_bf16(pA[i * 64], pB[i * 64], acc, 0, 0, 0);
            }
            const int col = L & 15, rw = quad << 2;
            #pragma unroll
            for (int r = 0; r < 4; r++)
                smf[1152 + w * 256 + (rw + r) * 16 + col] = acc[r];
            __syncthreads();
            if (t < 16) {                            // reduce 8 partials + squash
                float sv[S_]; float msq = 0.f;
                #pragma unroll
                for (int s = 0; s < S_; s++) {
                    float a = 0.f;
                    #pragma unroll
                    for (int w8 = 0; w8 < 8; w8++)
                        a += smf[1152 + w8 * 256 + s * 16 + t];
                    if (it == 0) a *= 0.1f;
                    sv[s] = a; msq += a * a;
                }
                const float scale = msq / ((1.f + msq) * sqrtf(msq));
                if (it < 2) {
                    #pragma unroll
                    for (int s = 0; s < S_; s++)
                        smf[3456 + t * 16 + s] = sv[s] * scale;   // vtmp[bl][s]
                } else {
                    const int b = nt * 16 + t;
                    float o16[S_];
                    #pragma unroll
                    for (int s = 0; s < S_; s++) o16[s] = sv[s] * scale;
                    float* dst = &out[((size_t)b * J_ + j) * S_];
                    #pragma unroll
                    for (int r4 = 0; r4 < 4; r4++)
                        *(float4*)(dst + r4 * 4) = *(float4*)(o16 + r4 * 4);
                }
            }
            if (it < 2 && t < 8) {   // pack bl-pairs -> dword atomic stores (LLC)
                const int kb = nt >> 1;
                const int e0 = (2 * t) & 7;
                const int lh = ((nt & 1) << 1) | (t >> 2);
                #pragma unroll
                for (int s = 0; s < S_; s++) {
                    unsigned int d = pack2(smf[3456 + (2 * t) * 16 + s],
                                           smf[3456 + (2 * t + 1) * 16 + s]);
                    int sidx = ((j * 16 + kb) * 64 + (s | (lh << 4))) * 8 + e0;
                    __hip_atomic_store(&Vf_dw[sidx >> 1], d,
                                       __ATOMIC_RELAXED, __HIP_MEMORY_SCOPE_AGENT);
                }
            }
        }
        if (it == 2) return;
        grid_bar(bar);

        // ================= T phase: 720 tasks (j, ntg) =================
        for (int task = bid; task < 720; task += NBL) {
            __syncthreads();
            const int j = task / 72, ntg = task % 72;
            for (int d = t; d < 4096; d += NT)       // stage Vf-j via LLC (16 KB)
                smu[d] = __hip_atomic_load(&Vf_dw[j * 4096 + d],
                         __ATOMIC_RELAXED, __HIP_MEMORY_SCOPE_AGENT);
            __syncthreads();
            const int nt = ntg * 8 + w;
            const short8* pB  = Bt + ((size_t)nt * KBT) * 64 + L;
            const short8* pAl = (const short8*)smu + L;
            floatx4 a = {0.f, 0.f, 0.f, 0.f};
            #pragma unroll
            for (int kb = 0; kb < KBT; kb++)
                a = __builtin_amdgcn_mfma_f32_16x16x32_bf16(pAl[kb * 64], pB[kb * 64], a, 0, 0, 0);
            const int col = L & 15, rw = quad << 2;
            #pragma unroll
            for (int r = 0; r < 4; r++)
                smf[4096 + (rw + r) * 132 + w * 16 + col] = a[r];
            __syncthreads();
            if (t < 128) {
                const int n0 = ntg * 128;
                const int i = n0 / C_, c0 = n0 % C_;
                const int c = c0 + t;
                const unsigned short* wp = W2 + ((size_t)(j * 8 + i) * C_ + c) * 16;
                uint4 w0 = *(const uint4*)wp;
                uint4 w1 = *(const uint4*)(wp + 8);
                unsigned int uw[8] = {w0.x, w0.y, w0.z, w0.w, w1.x, w1.y, w1.z, w1.w};
                float sum = 0.f;
                #pragma unroll
                for (int h = 0; h < 8; h++) {
                    sum += smf[4096 + (2 * h) * 132 + t]     * __uint_as_float(uw[h] << 16);
                    sum += smf[4096 + (2 * h + 1) * 132 + t] * __uint_as_float(uw[h] & 0xffff0000u);
                }
                atomicAdd(&b_ij[c * J_ + j], sum * (1.0f / 512.f));
            }
        }
        grid_bar(bar);
    }
}

// ---------------------------------------------------------------------------
extern "C" void kernel_launch(void* const* d_in, const int* in_sizes, int n_in,
                              void* d_out, int out_size, void* d_ws, size_t ws_size,
                              hipStream_t stream) {
    const float* x = (const float*)d_in[0];   // [512][8][1152]
    const float* W = (const float*)d_in[1];   // [1152][10][16][8]
    float* out = (float*)d_out;               // [512][10][16][1]
    float* ws  = (float*)d_ws;

    float* Bs_f = ws;                    // 2,359,296
    float* Bt_f = Bs_f + 2359296;        // 2,359,296
    float* Wf_f = Bt_f + 2359296;        //   737,280
    float* W2_f = Wf_f + 737280;         //   737,280
    float* Vf_f = W2_f + 737280;         //    40,960 (81,920 bf16)
    float* bij  = Vf_f + 40960;          //    11,520
    int*   bar  = (int*)(bij + 11520);   //        16
    // total ~25 MB

    k_pack<<<721, 512, 0, stream>>>(x, W, (uint4*)Bs_f, (uint4*)Bt_f,
                                    (uint4*)Wf_f, (unsigned short*)W2_f, bij, bar);

    k_main<<<NBL, NT, 0, stream>>>((const short8*)Wf_f, (const short8*)Bs_f,
                                   (const short8*)Bt_f, (const unsigned short*)W2_f,
                                   (unsigned int*)Vf_f, bij, out, bar);
}

// Round 8
// 142.989 us; speedup vs baseline: 1.6005x; 1.6005x over previous
//
#include <hip/hip_runtime.h>
#include <math.h>

#define B_  512
#define I_  8
#define C_  1152
#define J_  10
#define S_  16
#define K1  9216
#define NKB 288     // sgemm K-blocks (K=9216/32)
#define KBT 16      // tgemm K-blocks (K=512/32)

typedef short short8 __attribute__((ext_vector_type(8)));
typedef float floatx4 __attribute__((ext_vector_type(4)));

__device__ inline unsigned short f2bf(float f) {
    unsigned int u = __float_as_uint(f);
    return (unsigned short)((u + 0x7FFFu + ((u >> 16) & 1u)) >> 16);
}
__device__ inline unsigned int pack2(float a, float b) {
    return (unsigned int)f2bf(a) | ((unsigned int)f2bf(b) << 16);
}

// ---------------------------------------------------------------------------
// PACK: 721 blocks x 512 threads (unchanged from r6 — reads x once).
__global__ __launch_bounds__(512) void k_pack(const float* __restrict__ x,
                                              const float* __restrict__ W,
                                              uint4* __restrict__ Bs,
                                              uint4* __restrict__ Bt,
                                              uint4* __restrict__ Wf,
                                              unsigned short* __restrict__ W2,
                                              float* __restrict__ b_ij) {
    __shared__ float lds[10240];
    const int task = blockIdx.x;
    const int t = threadIdx.x;
    const int w = t >> 6, L = t & 63, quad = L >> 4;

    if (task < 576) {                       // ---- x tile -> Bs + Bt
        const int bt = task / 36, kt = task % 36;
        const int b0 = bt * 32, k0 = kt * 256;
        #pragma unroll
        for (int p = 0; p < 4; p++) {
            int f4 = p * 512 + t;
            int row = f4 >> 6, c4 = (f4 & 63) << 2;
            *(float4*)&lds[row * 260 + c4] =
                *(const float4*)&x[(size_t)(b0 + row) * K1 + k0 + c4];
        }
        __syncthreads();
        #pragma unroll
        for (int p = 0; p < 2; p++) {
            const int bl = p * 16 + (L & 15);
            const float* s = &lds[bl * 260 + w * 32 + quad * 8];
            uint4 o;
            o.x = pack2(s[0], s[1]); o.y = pack2(s[2], s[3]);
            o.z = pack2(s[4], s[5]); o.w = pack2(s[6], s[7]);
            Bs[((size_t)(bt * 2 + p) * NKB + kt * 8 + w) * 64 + L] = o;
        }
        #pragma unroll
        for (int p = 0; p < 2; p++) {
            const int ntl = w * 2 + p;
            const int nl = ntl * 16 + (L & 15);
            float v[8];
            #pragma unroll
            for (int e = 0; e < 8; e++) v[e] = lds[(quad * 8 + e) * 260 + nl];
            uint4 o;
            o.x = pack2(v[0], v[1]); o.y = pack2(v[2], v[3]);
            o.z = pack2(v[4], v[5]); o.w = pack2(v[6], v[7]);
            Bt[((size_t)(kt * 16 + ntl) * KBT + bt) * 64 + L] = o;
        }
    } else if (task < 720) {                // ---- W chunk -> Wf + W2
        const int c0 = (task - 576) * 8;
        #pragma unroll
        for (int p = 0; p < 5; p++) {
            int f4 = p * 512 + t;
            int cc = f4 / 320, off4 = (f4 % 320) << 2;
            *(float4*)&lds[cc * 1280 + off4] =
                *(const float4*)&W[(size_t)(c0 + cc) * 1280 + off4];
        }
        __syncthreads();
        #pragma unroll
        for (int p = 0; p < 3; p++) {
            int o = p * 512 + t;
            if (o < 1280) {
                int j = o >> 7, i = (o >> 4) & 7, m = o & 15;
                int k0w = i * C_ + c0;
                int Lw = m | (((k0w >> 3) & 3) << 4);
                float v[8];
                #pragma unroll
                for (int e = 0; e < 8; e++)
                    v[e] = lds[e * 1280 + j * 128 + m * 8 + i];
                uint4 og;
                og.x = pack2(v[0], v[1]); og.y = pack2(v[2], v[3]);
                og.z = pack2(v[4], v[5]); og.w = pack2(v[6], v[7]);
                Wf[((size_t)j * NKB + (k0w >> 5)) * 64 + Lw] = og;
            }
        }
        #pragma unroll
        for (int p = 0; p < 2; p++) {
            int o = p * 512 + t;
            if (o < 640) {
                int j = o >> 6, i = (o >> 3) & 7, cc = o & 7;
                unsigned int r8[8];
                #pragma unroll
                for (int h = 0; h < 8; h++)
                    r8[h] = pack2(lds[cc * 1280 + j * 128 + (2 * h) * 8 + i],
                                  lds[cc * 1280 + j * 128 + (2 * h + 1) * 8 + i]);
                unsigned short* dst = W2 + ((size_t)(j * 8 + i) * C_ + c0 + cc) * 16;
                *(uint4*)dst       = make_uint4(r8[0], r8[1], r8[2], r8[3]);
                *(uint4*)(dst + 8) = make_uint4(r8[4], r8[5], r8[6], r8[7]);
            }
        }
    } else {                                // ---- zero b_ij
        for (int idx = t; idx < C_ * J_; idx += 512) b_ij[idx] = 0.0f;
    }
}

// ---------------------------------------------------------------------------
// SGEMM + fused fold + reduce + squash.
// grid 160 = j(10) x ntp(16); block 512 (8 waves = 8-way K-split x 36 iters).
// mode 0: uniform cnorm=0.1; mode 1: softmax fold, write Vf; mode 2: write out.
__global__ __launch_bounds__(512) void k_sgemm_f(const short8* __restrict__ Wf,
                                                 const short8* __restrict__ Bs,
                                                 const float* __restrict__ b_ij,
                                                 unsigned short* __restrict__ Vf,
                                                 float* __restrict__ out,
                                                 int mode) {
    __shared__ float smf[1152 + 4096];   // cn[1152] + part[8 waves][2 nt][256]
    const int t = threadIdx.x, w = t >> 6, L = t & 63, quad = L >> 4;
    const int j = blockIdx.x >> 4;
    const int ntp = blockIdx.x & 15;

    if (mode) {
        for (int c = t; c < C_; c += 512) {
            float bv[J_], mx = -1e30f;
            #pragma unroll
            for (int jj = 0; jj < J_; jj++) {
                bv[jj] = b_ij[c * J_ + jj]; mx = fmaxf(mx, bv[jj]);
            }
            float sum = 0.0f;
            #pragma unroll
            for (int jj = 0; jj < J_; jj++) sum += __expf(bv[jj] - mx);
            smf[c] = __expf(bv[j] - mx) / sum;
        }
    }
    __syncthreads();

    const short8* pA  = Wf + ((size_t)j * NKB + w * 36) * 64 + L;
    const short8* pB0 = Bs + ((size_t)(ntp * 2) * NKB + w * 36) * 64 + L;
    const short8* pB1 = pB0 + (size_t)NKB * 64;
    floatx4 c0 = {0.f, 0.f, 0.f, 0.f}, c1 = c0;

    if (mode) {
        #pragma unroll 4
        for (int i = 0; i < 36; i++) {
            short8 a = pA[i * 64];
            const int cb = i * 32 + quad * 8;     // (w*36*32) % 1152 == 0
            float4 cl = *(const float4*)&smf[cb];
            float4 ch = *(const float4*)&smf[cb + 4];
            float cn8[8] = {cl.x, cl.y, cl.z, cl.w, ch.x, ch.y, ch.z, ch.w};
            unsigned int* au = (unsigned int*)&a;
            short8 a2; unsigned int* ao = (unsigned int*)&a2;
            #pragma unroll
            for (int h = 0; h < 4; h++) {
                float f0 = __uint_as_float(au[h] << 16)         * cn8[2 * h];
                float f1 = __uint_as_float(au[h] & 0xffff0000u) * cn8[2 * h + 1];
                ao[h] = pack2(f0, f1);
            }
            c0 = __builtin_amdgcn_mfma_f32_16x16x32_bf16(a2, pB0[i * 64], c0, 0, 0, 0);
            c1 = __builtin_amdgcn_mfma_f32_16x16x32_bf16(a2, pB1[i * 64], c1, 0, 0, 0);
        }
    } else {
        #pragma unroll 4
        for (int i = 0; i < 36; i++) {
            short8 a = pA[i * 64];
            c0 = __builtin_amdgcn_mfma_f32_16x16x32_bf16(a, pB0[i * 64], c0, 0, 0, 0);
            c1 = __builtin_amdgcn_mfma_f32_16x16x32_bf16(a, pB1[i * 64], c1, 0, 0, 0);
        }
    }

    const int col = L & 15, rw = quad << 2;
    float* base = &smf[1152 + w * 512];
    #pragma unroll
    for (int r = 0; r < 4; r++) {
        base[      (rw + r) * 16 + col] = c0[r];
        base[256 + (rw + r) * 16 + col] = c1[r];
    }
    __syncthreads();

    if (t < 32) {
        const int ntl = t >> 4, bl = t & 15;
        float sv[S_]; float msq = 0.f;
        #pragma unroll
        for (int s = 0; s < S_; s++) {
            float a = 0.f;
            #pragma unroll
            for (int w8 = 0; w8 < 8; w8++)
                a += smf[1152 + w8 * 512 + ntl * 256 + s * 16 + bl];
            if (mode == 0) a *= 0.1f;
            sv[s] = a; msq += a * a;
        }
        const float scale = msq / ((1.f + msq) * sqrtf(msq));
        const int b = ntp * 32 + t;          // global b (0..511)
        if (mode < 2) {
            const int kb = b >> 5, lh = (b >> 3) & 3, e = b & 7;
            #pragma unroll
            for (int s = 0; s < S_; s++)
                Vf[((size_t)(j * KBT + kb) * 64 + (s | (lh << 4))) * 8 + e] =
                    f2bf(sv[s] * scale);
        } else {
            float o16[S_];
            #pragma unroll
            for (int s = 0; s < S_; s++) o16[s] = sv[s] * scale;
            float* dst = &out[((size_t)b * J_ + j) * S_];
            #pragma unroll
            for (int r4 = 0; r4 < 4; r4++)
                *(float4*)(dst + r4 * 4) = *(float4*)(o16 + r4 * 4);
        }
    }
}

// ---------------------------------------------------------------------------
// TGEMM + fused b_ij update, LDS-free: in-register W2 contraction +
// cross-quad shfl reduce (lanes L, L^16, L^32, L^48 share column c).
// grid(72 ntg, 10 j), 512 threads (8 waves), no __syncthreads.
__global__ __launch_bounds__(512) void k_tgemm_bup(const short8* __restrict__ Vf,
                                                   const short8* __restrict__ Bt,
                                                   const unsigned short* __restrict__ W2,
                                                   float* __restrict__ b_ij) {
    const int t = threadIdx.x, w = t >> 6, L = t & 63;
    const int j = blockIdx.y, ntg = blockIdx.x;
    const int nt = ntg * 8 + w;
    const short8* pA = Vf + (size_t)j * KBT * 64 + L;
    const short8* pB = Bt + (size_t)nt * KBT * 64 + L;
    floatx4 a = {0.f, 0.f, 0.f, 0.f};
    #pragma unroll
    for (int kb = 0; kb < KBT; kb++)
        a = __builtin_amdgcn_mfma_f32_16x16x32_bf16(pA[kb * 64], pB[kb * 64], a, 0, 0, 0);
    // lane holds T[s = rw..rw+3][n = nt*16 + col]; n = i*1152 + c
    const int col = L & 15, rw = (L >> 4) << 2;
    const int i = nt / 72;
    const int c = (nt % 72) * 16 + col;
    const unsigned short* wp = W2 + ((size_t)(j * 8 + i) * C_ + c) * 16 + rw;
    uint2 wv = *(const uint2*)wp;        // 4 bf16: s = rw..rw+3
    float p = a[0] * __uint_as_float((unsigned int)wv.x << 16)
            + a[1] * __uint_as_float(wv.x & 0xffff0000u)
            + a[2] * __uint_as_float((unsigned int)wv.y << 16)
            + a[3] * __uint_as_float(wv.y & 0xffff0000u);
    p += __shfl_xor(p, 16);
    p += __shfl_xor(p, 32);
    if ((L >> 4) == 0)
        atomicAdd(&b_ij[c * J_ + j], p * (1.0f / 512.f));
}

// ---------------------------------------------------------------------------
extern "C" void kernel_launch(void* const* d_in, const int* in_sizes, int n_in,
                              void* d_out, int out_size, void* d_ws, size_t ws_size,
                              hipStream_t stream) {
    const float* x = (const float*)d_in[0];   // [512][8][1152]
    const float* W = (const float*)d_in[1];   // [1152][10][16][8]
    float* out = (float*)d_out;               // [512][10][16][1]
    float* ws  = (float*)d_ws;

    float* Bs_f = ws;                    // 2,359,296
    float* Bt_f = Bs_f + 2359296;        // 2,359,296
    float* Wf_f = Bt_f + 2359296;        //   737,280
    float* W2_f = Wf_f + 737280;         //   737,280
    float* Vf_f = W2_f + 737280;         //    40,960
    float* bij  = Vf_f + 40960;          //    11,520
    // total ~25 MB

    k_pack<<<721, 512, 0, stream>>>(x, W, (uint4*)Bs_f, (uint4*)Bt_f,
                                    (uint4*)Wf_f, (unsigned short*)W2_f, bij);

    k_sgemm_f<<<160, 512, 0, stream>>>((const short8*)Wf_f, (const short8*)Bs_f,
                                       bij, (unsigned short*)Vf_f, out, 0);
    k_tgemm_bup<<<dim3(72, 10), 512, 0, stream>>>(
        (const short8*)Vf_f, (const short8*)Bt_f, (const unsigned short*)W2_f, bij);

    k_sgemm_f<<<160, 512, 0, stream>>>((const short8*)Wf_f, (const short8*)Bs_f,
                                       bij, (unsigned short*)Vf_f, out, 1);
    k_tgemm_bup<<<dim3(72, 10), 512, 0, stream>>>(
        (const short8*)Vf_f, (const short8*)Bt_f, (const unsigned short*)W2_f, bij);

    k_sgemm_f<<<160, 512, 0, stream>>>((const short8*)Wf_f, (const short8*)Bs_f,
                                       bij, (unsigned short*)Vf_f, out, 2);
}